// Round 2
// baseline (343.359 us; speedup 1.0000x reference)
//
#include <hip/hip_runtime.h>
#include <math.h>

#define NBATCH 4096
#define TNUM   128
#define NOBSC  10
#define MAXIT  30

// ws layout (floats)
#define WS_MX   0      // 16x16
#define WS_MY   256    // 16x16
#define WS_MGX  512    // 16x16  (Mx*Gx)
#define WS_MGY  768    // 16x16  (My*Gy)
#define WS_NX   1024   // 16x8
#define WS_NY   1152   // 16x9
#define WS_NX0  1296   // 16x8
#define WS_NY0  1424   // 16x9
// total 1568 floats

union F4 { float4 v; float f[4]; };

// ---------------- setup kernel: build + invert KKT matrices (fp64 GJ) -------
__global__ __launch_bounds__(64) void planner_setup(
    const float* __restrict__ P, const float* __restrict__ Pd, const float* __restrict__ Pdd,
    float* __restrict__ ws)
{
  const int mid = blockIdx.x;   // 0: (cost_sm,Ax)->Nx0  1: (cost_sm,Ay)->Ny0
                                // 2: (cost_x,Ax)->Mx,Nx,MGx 3: (cost_y,Ay)->My,Ny,MGy
  const int tid = threadIdx.x;
  __shared__ double C[16][16];
  __shared__ double G[16][16];
  __shared__ double Ae[9][16];
  __shared__ double aug[25][50];
  __shared__ int pivs;

  const bool isY = (mid & 1);
  const int  m   = isY ? 9 : 8;
  const int  n   = 16 + m;
  const int  w   = 2 * n;

  // Gram matrices + cost matrix
  for (int e = tid; e < 256; e += 64) {
    const int j = e >> 4, k = e & 15;
    double gdd = 0.0, gd = 0.0, g0 = 0.0;
    for (int t = 0; t < TNUM; ++t) {
      gdd += (double)Pdd[t*16+j] * (double)Pdd[t*16+k];
      gd  += (double)Pd [t*16+j] * (double)Pd [t*16+k];
      g0  += (double)P  [t*16+j] * (double)P  [t*16+k];
    }
    const double cs = 100.0 * (gdd + ((j == k) ? 0.1 : 0.0));   // cost_sm
    const double g  = gdd + gd + (isY ? 12.0 : 10.0) * g0;      // Gx or Gy
    G[j][k] = g;
    C[j][k] = (mid >= 2) ? (cs + (gdd + gd + (isY ? 12.0 : 10.0) * g0)) : cs;
  }
  if (tid < 16) {
    const int j = tid;
    Ae[0][j] = (double)P  [0*16+j];
    Ae[1][j] = (double)Pd [0*16+j];
    Ae[2][j] = (double)Pdd[0*16+j];
    if (!isY) {
      Ae[3][j] = (double)Pd[127*16+j];
      for (int r = 4; r < 8; ++r) Ae[r][j] = (j == r) ? 1.0 : 0.0;
    } else {
      Ae[3][j] = (double)P [127*16+j];
      Ae[4][j] = (double)Pd[127*16+j];
      for (int r = 5; r < 9; ++r) Ae[r][j] = (j == (r-1)) ? 1.0 : 0.0;
    }
  }
  __syncthreads();

  // build augmented [KKT | I]
  for (int e = tid; e < n * w; e += 64) {
    const int r = e / w, c = e % w;
    double val;
    if (c < n) {
      if (r < 16) val = (c < 16) ? C[r][c] : Ae[c-16][r];
      else        val = (c < 16) ? Ae[r-16][c] : 0.0;
    } else {
      val = ((c - n) == r) ? 1.0 : 0.0;
    }
    aug[r][c] = val;
  }
  __syncthreads();

  // Gauss-Jordan with partial pivoting
  for (int k = 0; k < n; ++k) {
    if (tid == 0) {
      int p = k; double best = fabs(aug[k][k]);
      for (int r = k+1; r < n; ++r) { double a = fabs(aug[r][k]); if (a > best) { best = a; p = r; } }
      pivs = p;
    }
    __syncthreads();
    const int p = pivs;
    if (p != k) {
      for (int c = tid; c < w; c += 64) { double t = aug[k][c]; aug[k][c] = aug[p][c]; aug[p][c] = t; }
    }
    __syncthreads();
    const double ipiv = 1.0 / aug[k][k];
    for (int c = tid; c < w; c += 64) aug[k][c] *= ipiv;
    __syncthreads();
    for (int r = tid; r < n; r += 64) {
      if (r != k) {
        const double f = aug[r][k];
        for (int c = k; c < w; ++c) aug[r][c] -= f * aug[k][c];
      }
    }
    __syncthreads();
  }

  // write sub-blocks of the inverse (cols n.. of aug)
  if (mid == 0) {
    for (int e = tid; e < 16*8; e += 64) ws[WS_NX0 + e] = (float)aug[e >> 3][n + 16 + (e & 7)];
  } else if (mid == 1) {
    for (int e = tid; e < 16*9; e += 64) ws[WS_NY0 + e] = (float)aug[e / 9][n + 16 + (e % 9)];
  } else if (mid == 2) {
    for (int e = tid; e < 256;  e += 64) ws[WS_MX + e] = (float)aug[e >> 4][n + (e & 15)];
    for (int e = tid; e < 16*8; e += 64) ws[WS_NX + e] = (float)aug[e >> 3][n + 16 + (e & 7)];
  } else {
    for (int e = tid; e < 256;  e += 64) ws[WS_MY + e] = (float)aug[e >> 4][n + (e & 15)];
    for (int e = tid; e < 16*9; e += 64) ws[WS_NY + e] = (float)aug[e / 9][n + 16 + (e % 9)];
  }

  // MG = M * G  (fp64), for the fused per-iteration solve
  if (mid >= 2) {
    for (int e = tid; e < 256; e += 64) {
      const int j = e >> 4, k = e & 15;
      double s = 0.0;
      for (int mm = 0; mm < 16; ++mm) s += aug[j][n + mm] * G[mm][k];
      ws[(mid == 2 ? WS_MGX : WS_MGY) + e] = (float)s;
    }
  }
}

// ---------------- main kernel: 128 threads (2 waves) per batch element ------
__global__ __launch_bounds__(128, 4) void planner_main(
    const float* __restrict__ P, const float* __restrict__ Pd, const float* __restrict__ Pdd,
    const float* __restrict__ init_state, const float* __restrict__ fin_state,
    const float* __restrict__ cobs, const float* __restrict__ vobs,
    const float* __restrict__ yub_g, const float* __restrict__ ylb_g,
    const float* __restrict__ lamx_g, const float* __restrict__ lamy_g,
    const float* __restrict__ cxp_g, const float* __restrict__ cyp_g,
    const float* __restrict__ ws, float* __restrict__ out)
{
  const int b    = blockIdx.x;
  const int tid  = threadIdx.x;
  const int lane = tid & 63;
  const int wv   = tid >> 6;

  __shared__ float red[32*128];             // 16 KB: [o][t]
  __shared__ alignas(16) float cL[32];      // cx[0..15], cy[16..31]
  __shared__ alignas(16) float hL[32];      // lam - 2S
  __shared__ float pL[32];                  // cross-wave partials

  // basis rows for this lane's timestep t = tid
  float Pr[16], Pdr[16], Pddr[16];
  #pragma unroll
  for (int q = 0; q < 4; ++q) {
    const float4 a  = *reinterpret_cast<const float4*>(P   + tid*16 + 4*q);
    const float4 bb = *reinterpret_cast<const float4*>(Pd  + tid*16 + 4*q);
    const float4 cc = *reinterpret_cast<const float4*>(Pdd + tid*16 + 4*q);
    Pr  [4*q+0]=a.x;  Pr  [4*q+1]=a.y;  Pr  [4*q+2]=a.z;  Pr  [4*q+3]=a.w;
    Pdr [4*q+0]=bb.x; Pdr [4*q+1]=bb.y; Pdr [4*q+2]=bb.z; Pdr [4*q+3]=bb.w;
    Pddr[4*q+0]=cc.x; Pddr[4*q+1]=cc.y; Pddr[4*q+2]=cc.z; Pddr[4*q+3]=cc.w;
  }

  // pre-scaled obstacle trajectories at this timestep
  float xot32[10], yot6[10];
  {
    const float tt = (float)tid * (10.0f/127.0f);
    #pragma unroll
    for (int oo = 0; oo < NOBSC; ++oo) {
      xot32[oo] = 3.2f * fmaf(vobs[b*20+oo],      tt, cobs[b*20+oo]);
      yot6 [oo] = 6.0f * fmaf(vobs[b*20+10+oo],   tt, cobs[b*20+10+oo]);
    }
  }
  const float yub = yub_g[b], ylb = ylb_g[b];

  const bool owner = (wv == 0) && (lane < 32);

  float lam = 0.f, constv = 0.f, acc_c = 0.f;
  if (owner) {
    float beq[9];
    const float vi  = init_state[b*4+2];
    const float psi = init_state[b*4+3];
    int nofs, n0ofs;
    if (lane < 16) {
      beq[0] = init_state[b*4+0];
      beq[1] = vi * cosf(psi);
      beq[2] = 0.f;
      beq[3] = fin_state[b*3+0];
      #pragma unroll
      for (int i2 = 0; i2 < 4; ++i2) beq[4+i2] = cxp_g[b*4+i2];
      beq[8] = 0.f;                       // pad (multiplies valid-but-unused ws)
      nofs  = WS_NX  + lane*8;
      n0ofs = WS_NX0 + lane*8;
    } else {
      beq[0] = init_state[b*4+1];
      beq[1] = vi * sinf(psi);
      beq[2] = 0.f;
      beq[3] = fin_state[b*3+1];
      beq[4] = 0.f;
      #pragma unroll
      for (int i2 = 0; i2 < 4; ++i2) beq[5+i2] = cyp_g[b*4+i2];
      nofs  = WS_NY  + (lane-16)*9;
      n0ofs = WS_NY0 + (lane-16)*9;
    }
    float cv = 0.f, c0 = 0.f;
    #pragma unroll
    for (int mm = 0; mm < 9; ++mm) {
      const float bm = beq[mm];
      cv = fmaf(ws[nofs  + mm], bm, cv);
      c0 = fmaf(ws[n0ofs + mm], bm, c0);
    }
    constv = cv;
    acc_c  = c0;
    cL[lane] = c0;
    lam = (lane < 16) ? lamx_g[b*16 + lane] : lamy_g[b*16 + (lane-16)];
  }

  #pragma unroll 1
  for (int it = 0; it < MAXIT; ++it) {
    __syncthreads();   // c from prev iter visible; red reusable

    // forward: x, xd, xdd, y, yd, ydd at this timestep
    float x=0.f, y=0.f, xd=0.f, yd=0.f, xdd=0.f, ydd=0.f;
    #pragma unroll
    for (int q = 0; q < 4; ++q) {
      F4 cx4, cy4;
      cx4.v = *reinterpret_cast<const float4*>(cL + 4*q);
      cy4.v = *reinterpret_cast<const float4*>(cL + 16 + 4*q);
      #pragma unroll
      for (int j = 0; j < 4; ++j) {
        const int jj = 4*q + j;
        const float cc = cx4.f[j], dd = cy4.f[j];
        x   = fmaf(Pr  [jj], cc, x);   y   = fmaf(Pr  [jj], dd, y);
        xd  = fmaf(Pdr [jj], cc, xd);  yd  = fmaf(Pdr [jj], dd, yd);
        xdd = fmaf(Pddr[jj], cc, xdd); ydd = fmaf(Pddr[jj], dd, ydd);
      }
    }

    // projections (residual factors)
    const float ria = rsqrtf(fmaxf(fmaf(xdd, xdd, ydd*ydd), 1e-36f));
    const float ga1 = 1.0f - fminf(1.0f, 18.0f * ria);
    const float riv = rsqrtf(fmaxf(fmaf(xd, xd, yd*yd), 1e-36f));
    const float gv1 = 1.0f - fminf(fmaxf(1.0f, 0.1f*riv), 30.0f*riv);

    // obstacles: e = max(0, AB/r - 1); accumulate scaled sums
    float Sxp = 0.f, Syp = 0.f;
    #pragma unroll
    for (int oo = 0; oo < NOBSC; ++oo) {
      const float bw = fmaf(3.2f, x, -xot32[oo]);
      const float aw = fmaf(6.0f, y, -yot6[oo]);
      const float ri = rsqrtf(fmaxf(fmaf(bw, bw, aw*aw), 1e-36f));
      const float e  = fmaxf(fmaf(19.2f, ri, -1.0f), 0.f);
      Sxp = fmaf(e, bw, Sxp);
      Syp = fmaf(e, aw, Syp);
    }
    const float c0p = -Sxp * 0.3125f;                        // -Sx
    const float rln = fmaxf(y - yub, 0.f) - fmaxf(ylb - y, 0.f);
    const float c2p = rln - Syp * (1.0f/6.0f);               // rln - Sy
    const float c0dd = xdd * ga1, c0d = xd * gv1;
    const float c2dd = ydd * ga1, c2d = yd * gv1;

    // residual back-projection, fused straight into LDS (no v[] array)
    {
      float* col = red + tid;
      #pragma unroll
      for (int j = 0; j < 16; ++j) {
        col[j*128]      = fmaf(c0dd, Pddr[j], fmaf(c0d, Pdr[j], c0p * Pr[j]));
        col[(16+j)*128] = fmaf(c2dd, Pddr[j], fmaf(c2d, Pdr[j], c2p * Pr[j]));
      }
    }
    __syncthreads();

    // reduce 32 sums over 128 columns: each lane sums a 32-chunk (rotated b128 reads)
    const int oo2 = tid & 31;
    const int qq  = tid >> 5;
    const float* rb = red + oo2*128 + qq*32;
    const int rot = oo2 & 7;
    float s0=0.f, s1=0.f, s2=0.f, s3=0.f;
    #pragma unroll
    for (int mch = 0; mch < 8; ++mch) {
      const float4 t = *reinterpret_cast<const float4*>(rb + (((mch + rot) & 7) << 2));
      s0 += t.x; s1 += t.y; s2 += t.z; s3 += t.w;
    }
    float s = (s0 + s1) + (s2 + s3);
    s += __shfl_xor(s, 32);                 // combine q-pairs within wave
    if (wv == 1 && lane < 32) pL[lane] = s; // wave1's q2+q3 partial
    __syncthreads();

    if (owner) {
      const float S = s + pL[lane];         // full dlambda sum
      lam -= S;
      hL[lane] = lam - S;                   // = lam_old - 2S

      // fused solve: c' = MG*c + M*h + const
      const bool xs = (lane < 16);
      const int  r  = xs ? lane : (lane - 16);
      const float* Mrow  = ws + (xs ? WS_MX  : WS_MY)  + r*16;
      const float* MGrow = ws + (xs ? WS_MGX : WS_MGY) + r*16;
      const float* hp = hL + (xs ? 0 : 16);
      const float* cp = cL + (xs ? 0 : 16);
      float acc = constv;
      #pragma unroll
      for (int q = 0; q < 4; ++q) {
        F4 m4, g4, h4, c4;
        m4.v = *reinterpret_cast<const float4*>(Mrow  + 4*q);
        g4.v = *reinterpret_cast<const float4*>(MGrow + 4*q);
        h4.v = *reinterpret_cast<const float4*>(hp + 4*q);
        c4.v = *reinterpret_cast<const float4*>(cp + 4*q);
        #pragma unroll
        for (int j = 0; j < 4; ++j)
          acc = fmaf(g4.f[j], c4.f[j], fmaf(m4.f[j], h4.f[j], acc));
      }
      acc_c = acc;
      cL[lane] = acc;                       // visible to all at next loop-top barrier
    }
  }

  if (owner) out[b*32 + lane] = acc_c;
}

extern "C" void kernel_launch(void* const* d_in, const int* in_sizes, int n_in,
                              void* d_out, int out_size, void* d_ws, size_t ws_size,
                              hipStream_t stream) {
  const float* P    = (const float*)d_in[0];
  const float* Pd   = (const float*)d_in[1];
  const float* Pdd  = (const float*)d_in[2];
  const float* init = (const float*)d_in[3];
  const float* fin  = (const float*)d_in[4];
  const float* cobs = (const float*)d_in[5];
  const float* vobs = (const float*)d_in[6];
  const float* yub  = (const float*)d_in[7];
  const float* ylb  = (const float*)d_in[8];
  const float* lamx = (const float*)d_in[9];
  const float* lamy = (const float*)d_in[10];
  const float* cxp  = (const float*)d_in[11];
  const float* cyp  = (const float*)d_in[12];
  float* ws  = (float*)d_ws;
  float* o   = (float*)d_out;

  planner_setup<<<dim3(4), dim3(64), 0, stream>>>(P, Pd, Pdd, ws);
  planner_main<<<dim3(NBATCH), dim3(128), 0, stream>>>(
      P, Pd, Pdd, init, fin, cobs, vobs, yub, ylb, lamx, lamy, cxp, cyp, ws, o);
}

// Round 3
// 245.473 us; speedup vs baseline: 1.3988x; 1.3988x over previous
//
#include <hip/hip_runtime.h>
#include <math.h>

#define NBATCH 4096
#define TNUM   128
#define NOBSC  10
#define MAXIT  30

// ws layout (floats)
#define WS_MX   0      // 16x16
#define WS_MY   256    // 16x16
#define WS_MGX  512    // 16x16  (Mx*Gx)
#define WS_MGY  768    // 16x16  (My*Gy)
#define WS_NX   1024   // 16x8
#define WS_NY   1152   // 16x9
#define WS_NX0  1296   // 16x8
#define WS_NY0  1424   // 16x9
// total 1568 floats

#define RSTRIDE 132    // padded row stride for reduction buffer (33 x 16B)

union F4 { float4 v; float f[4]; };

// ---------------- setup kernel: build + invert KKT matrices (fp64 GJ) -------
__global__ __launch_bounds__(64) void planner_setup(
    const float* __restrict__ P, const float* __restrict__ Pd, const float* __restrict__ Pdd,
    float* __restrict__ ws)
{
  const int mid = blockIdx.x;   // 0: (cost_sm,Ax)->Nx0  1: (cost_sm,Ay)->Ny0
                                // 2: (cost_x,Ax)->Mx,Nx,MGx 3: (cost_y,Ay)->My,Ny,MGy
  const int tid = threadIdx.x;
  __shared__ double C[16][16];
  __shared__ double G[16][16];
  __shared__ double Ae[9][16];
  __shared__ double aug[25][50];
  __shared__ int pivs;

  const bool isY = (mid & 1);
  const int  m   = isY ? 9 : 8;
  const int  n   = 16 + m;
  const int  w   = 2 * n;

  // Gram matrices + cost matrix
  for (int e = tid; e < 256; e += 64) {
    const int j = e >> 4, k = e & 15;
    double gdd = 0.0, gd = 0.0, g0 = 0.0;
    for (int t = 0; t < TNUM; ++t) {
      gdd += (double)Pdd[t*16+j] * (double)Pdd[t*16+k];
      gd  += (double)Pd [t*16+j] * (double)Pd [t*16+k];
      g0  += (double)P  [t*16+j] * (double)P  [t*16+k];
    }
    const double cs = 100.0 * (gdd + ((j == k) ? 0.1 : 0.0));   // cost_sm
    const double g  = gdd + gd + (isY ? 12.0 : 10.0) * g0;      // Gx or Gy
    G[j][k] = g;
    C[j][k] = (mid >= 2) ? (cs + g) : cs;
  }
  if (tid < 16) {
    const int j = tid;
    Ae[0][j] = (double)P  [0*16+j];
    Ae[1][j] = (double)Pd [0*16+j];
    Ae[2][j] = (double)Pdd[0*16+j];
    if (!isY) {
      Ae[3][j] = (double)Pd[127*16+j];
      for (int r = 4; r < 8; ++r) Ae[r][j] = (j == r) ? 1.0 : 0.0;
    } else {
      Ae[3][j] = (double)P [127*16+j];
      Ae[4][j] = (double)Pd[127*16+j];
      for (int r = 5; r < 9; ++r) Ae[r][j] = (j == (r-1)) ? 1.0 : 0.0;
    }
  }
  __syncthreads();

  // build augmented [KKT | I]
  for (int e = tid; e < n * w; e += 64) {
    const int r = e / w, c = e % w;
    double val;
    if (c < n) {
      if (r < 16) val = (c < 16) ? C[r][c] : Ae[c-16][r];
      else        val = (c < 16) ? Ae[r-16][c] : 0.0;
    } else {
      val = ((c - n) == r) ? 1.0 : 0.0;
    }
    aug[r][c] = val;
  }
  __syncthreads();

  // Gauss-Jordan with partial pivoting
  for (int k = 0; k < n; ++k) {
    if (tid == 0) {
      int p = k; double best = fabs(aug[k][k]);
      for (int r = k+1; r < n; ++r) { double a = fabs(aug[r][k]); if (a > best) { best = a; p = r; } }
      pivs = p;
    }
    __syncthreads();
    const int p = pivs;
    if (p != k) {
      for (int c = tid; c < w; c += 64) { double t = aug[k][c]; aug[k][c] = aug[p][c]; aug[p][c] = t; }
    }
    __syncthreads();
    const double ipiv = 1.0 / aug[k][k];
    for (int c = tid; c < w; c += 64) aug[k][c] *= ipiv;
    __syncthreads();
    for (int r = tid; r < n; r += 64) {
      if (r != k) {
        const double f = aug[r][k];
        for (int c = k; c < w; ++c) aug[r][c] -= f * aug[k][c];
      }
    }
    __syncthreads();
  }

  // write sub-blocks of the inverse (cols n.. of aug)
  if (mid == 0) {
    for (int e = tid; e < 16*8; e += 64) ws[WS_NX0 + e] = (float)aug[e >> 3][n + 16 + (e & 7)];
  } else if (mid == 1) {
    for (int e = tid; e < 16*9; e += 64) ws[WS_NY0 + e] = (float)aug[e / 9][n + 16 + (e % 9)];
  } else if (mid == 2) {
    for (int e = tid; e < 256;  e += 64) ws[WS_MX + e] = (float)aug[e >> 4][n + (e & 15)];
    for (int e = tid; e < 16*8; e += 64) ws[WS_NX + e] = (float)aug[e >> 3][n + 16 + (e & 7)];
  } else {
    for (int e = tid; e < 256;  e += 64) ws[WS_MY + e] = (float)aug[e >> 4][n + (e & 15)];
    for (int e = tid; e < 16*9; e += 64) ws[WS_NY + e] = (float)aug[e / 9][n + 16 + (e % 9)];
  }

  // MG = M * G  (fp64), for the fused per-iteration solve
  if (mid >= 2) {
    for (int e = tid; e < 256; e += 64) {
      const int j = e >> 4, k = e & 15;
      double s = 0.0;
      for (int mm = 0; mm < 16; ++mm) s += aug[j][n + mm] * G[mm][k];
      ws[(mid == 2 ? WS_MGX : WS_MGY) + e] = (float)s;
    }
  }
}

// ---------------- main kernel: 128 threads (2 waves) per batch element ------
__global__ __launch_bounds__(128, 2) void planner_main(
    const float* __restrict__ P, const float* __restrict__ Pd, const float* __restrict__ Pdd,
    const float* __restrict__ init_state, const float* __restrict__ fin_state,
    const float* __restrict__ cobs, const float* __restrict__ vobs,
    const float* __restrict__ yub_g, const float* __restrict__ ylb_g,
    const float* __restrict__ lamx_g, const float* __restrict__ lamy_g,
    const float* __restrict__ cxp_g, const float* __restrict__ cyp_g,
    const float* __restrict__ ws, float* __restrict__ out)
{
  const int b    = blockIdx.x;
  const int tid  = threadIdx.x;
  const int lane = tid & 63;
  const int wv   = tid >> 6;

  __shared__ alignas(16) float red[32*RSTRIDE];   // padded [o][t]
  __shared__ alignas(16) float cL[32];            // cx[0..15], cy[16..31]
  __shared__ alignas(16) float hL[32];            // lam - 2S
  __shared__ float pL[32];                        // cross-wave partials

  // basis rows for this lane's timestep t = tid
  float Pr[16], Pdr[16], Pddr[16];
  #pragma unroll
  for (int q = 0; q < 4; ++q) {
    const float4 a  = *reinterpret_cast<const float4*>(P   + tid*16 + 4*q);
    const float4 bb = *reinterpret_cast<const float4*>(Pd  + tid*16 + 4*q);
    const float4 cc = *reinterpret_cast<const float4*>(Pdd + tid*16 + 4*q);
    Pr  [4*q+0]=a.x;  Pr  [4*q+1]=a.y;  Pr  [4*q+2]=a.z;  Pr  [4*q+3]=a.w;
    Pdr [4*q+0]=bb.x; Pdr [4*q+1]=bb.y; Pdr [4*q+2]=bb.z; Pdr [4*q+3]=bb.w;
    Pddr[4*q+0]=cc.x; Pddr[4*q+1]=cc.y; Pddr[4*q+2]=cc.z; Pddr[4*q+3]=cc.w;
  }

  // pre-scaled obstacle trajectories at this timestep
  float xot32[10], yot6[10];
  {
    const float tt = (float)tid * (10.0f/127.0f);
    #pragma unroll
    for (int oo = 0; oo < NOBSC; ++oo) {
      xot32[oo] = 3.2f * fmaf(vobs[b*20+oo],      tt, cobs[b*20+oo]);
      yot6 [oo] = 6.0f * fmaf(vobs[b*20+10+oo],   tt, cobs[b*20+10+oo]);
    }
  }
  const float yub = yub_g[b], ylb = ylb_g[b];

  const bool owner = (wv == 0) && (lane < 32);

  float lam = 0.f, constv = 0.f, acc_c = 0.f;
  if (owner) {
    float beq[9];
    const float vi  = init_state[b*4+2];
    const float psi = init_state[b*4+3];
    int nofs, n0ofs;
    if (lane < 16) {
      beq[0] = init_state[b*4+0];
      beq[1] = vi * cosf(psi);
      beq[2] = 0.f;
      beq[3] = fin_state[b*3+0];
      #pragma unroll
      for (int i2 = 0; i2 < 4; ++i2) beq[4+i2] = cxp_g[b*4+i2];
      beq[8] = 0.f;                       // pad (multiplies valid-but-unused ws)
      nofs  = WS_NX  + lane*8;
      n0ofs = WS_NX0 + lane*8;
    } else {
      beq[0] = init_state[b*4+1];
      beq[1] = vi * sinf(psi);
      beq[2] = 0.f;
      beq[3] = fin_state[b*3+1];
      beq[4] = 0.f;
      #pragma unroll
      for (int i2 = 0; i2 < 4; ++i2) beq[5+i2] = cyp_g[b*4+i2];
      nofs  = WS_NY  + (lane-16)*9;
      n0ofs = WS_NY0 + (lane-16)*9;
    }
    float cv = 0.f, c0 = 0.f;
    #pragma unroll
    for (int mm = 0; mm < 9; ++mm) {
      const float bm = beq[mm];
      cv = fmaf(ws[nofs  + mm], bm, cv);
      c0 = fmaf(ws[n0ofs + mm], bm, c0);
    }
    constv = cv;
    acc_c  = c0;
    cL[lane] = c0;
    lam = (lane < 16) ? lamx_g[b*16 + lane] : lamy_g[b*16 + (lane-16)];
  }

  #pragma unroll 1
  for (int it = 0; it < MAXIT; ++it) {
    __syncthreads();   // c from prev iter visible; red reusable

    // forward: x, xd, xdd, y, yd, ydd at this timestep
    float x=0.f, y=0.f, xd=0.f, yd=0.f, xdd=0.f, ydd=0.f;
    #pragma unroll
    for (int q = 0; q < 4; ++q) {
      F4 cx4, cy4;
      cx4.v = *reinterpret_cast<const float4*>(cL + 4*q);
      cy4.v = *reinterpret_cast<const float4*>(cL + 16 + 4*q);
      #pragma unroll
      for (int j = 0; j < 4; ++j) {
        const int jj = 4*q + j;
        const float cc = cx4.f[j], dd = cy4.f[j];
        x   = fmaf(Pr  [jj], cc, x);   y   = fmaf(Pr  [jj], dd, y);
        xd  = fmaf(Pdr [jj], cc, xd);  yd  = fmaf(Pdr [jj], dd, yd);
        xdd = fmaf(Pddr[jj], cc, xdd); ydd = fmaf(Pddr[jj], dd, ydd);
      }
    }

    // projections (residual factors)
    const float ria = rsqrtf(fmaxf(fmaf(xdd, xdd, ydd*ydd), 1e-36f));
    const float ga1 = 1.0f - fminf(1.0f, 18.0f * ria);
    const float riv = rsqrtf(fmaxf(fmaf(xd, xd, yd*yd), 1e-36f));
    const float gv1 = 1.0f - fminf(fmaxf(1.0f, 0.1f*riv), 30.0f*riv);

    // obstacles: e = max(0, AB/r - 1); accumulate scaled sums
    float Sxp = 0.f, Syp = 0.f;
    #pragma unroll
    for (int oo = 0; oo < NOBSC; ++oo) {
      const float bw = fmaf(3.2f, x, -xot32[oo]);
      const float aw = fmaf(6.0f, y, -yot6[oo]);
      const float ri = rsqrtf(fmaxf(fmaf(bw, bw, aw*aw), 1e-36f));
      const float e  = fmaxf(fmaf(19.2f, ri, -1.0f), 0.f);
      Sxp = fmaf(e, bw, Sxp);
      Syp = fmaf(e, aw, Syp);
    }
    const float c0p = -Sxp * 0.3125f;                        // -Sx
    const float rln = fmaxf(y - yub, 0.f) - fmaxf(ylb - y, 0.f);
    const float c2p = rln - Syp * (1.0f/6.0f);               // rln - Sy
    const float c0dd = xdd * ga1, c0d = xd * gv1;
    const float c2dd = ydd * ga1, c2d = yd * gv1;

    // residual back-projection, fused straight into LDS (no v[] array)
    {
      float* col = red + tid;
      #pragma unroll
      for (int j = 0; j < 16; ++j) {
        col[j*RSTRIDE]      = fmaf(c0dd, Pddr[j], fmaf(c0d, Pdr[j], c0p * Pr[j]));
        col[(16+j)*RSTRIDE] = fmaf(c2dd, Pddr[j], fmaf(c2d, Pdr[j], c2p * Pr[j]));
      }
    }
    __syncthreads();

    // reduce 32 sums over 128 columns: lane (oo2,qq) sums a 32-chunk.
    // bank-quad of chunk m for row oo2 = (oo2 + m) mod 8  -> every aligned
    // 8-lane group covers all 32 banks: conflict-free.
    const int oo2 = tid & 31;
    const int qq  = tid >> 5;
    const float* rb = red + oo2*RSTRIDE + qq*32;
    float s0=0.f, s1=0.f, s2=0.f, s3=0.f;
    #pragma unroll
    for (int mch = 0; mch < 8; ++mch) {
      const float4 t = *reinterpret_cast<const float4*>(rb + 4*mch);
      s0 += t.x; s1 += t.y; s2 += t.z; s3 += t.w;
    }
    float s = (s0 + s1) + (s2 + s3);
    s += __shfl_xor(s, 32);                 // combine q-pairs within wave
    if (wv == 1 && lane < 32) pL[lane] = s; // wave1's q2+q3 partial
    __syncthreads();

    if (owner) {
      const float S = s + pL[lane];         // full dlambda sum
      lam -= S;
      hL[lane] = lam - S;                   // = lam_old - 2S

      // fused solve: c' = MG*c + M*h + const
      const bool xs = (lane < 16);
      const int  r  = xs ? lane : (lane - 16);
      const float* Mrow  = ws + (xs ? WS_MX  : WS_MY)  + r*16;
      const float* MGrow = ws + (xs ? WS_MGX : WS_MGY) + r*16;
      const float* hp = hL + (xs ? 0 : 16);
      const float* cp = cL + (xs ? 0 : 16);
      float acc = constv;
      #pragma unroll
      for (int q = 0; q < 4; ++q) {
        F4 m4, g4, h4, c4;
        m4.v = *reinterpret_cast<const float4*>(Mrow  + 4*q);
        g4.v = *reinterpret_cast<const float4*>(MGrow + 4*q);
        h4.v = *reinterpret_cast<const float4*>(hp + 4*q);
        c4.v = *reinterpret_cast<const float4*>(cp + 4*q);
        #pragma unroll
        for (int j = 0; j < 4; ++j)
          acc = fmaf(g4.f[j], c4.f[j], fmaf(m4.f[j], h4.f[j], acc));
      }
      acc_c = acc;
      cL[lane] = acc;                       // visible to all at next loop-top barrier
    }
  }

  if (owner) out[b*32 + lane] = acc_c;
}

extern "C" void kernel_launch(void* const* d_in, const int* in_sizes, int n_in,
                              void* d_out, int out_size, void* d_ws, size_t ws_size,
                              hipStream_t stream) {
  const float* P    = (const float*)d_in[0];
  const float* Pd   = (const float*)d_in[1];
  const float* Pdd  = (const float*)d_in[2];
  const float* init = (const float*)d_in[3];
  const float* fin  = (const float*)d_in[4];
  const float* cobs = (const float*)d_in[5];
  const float* vobs = (const float*)d_in[6];
  const float* yub  = (const float*)d_in[7];
  const float* ylb  = (const float*)d_in[8];
  const float* lamx = (const float*)d_in[9];
  const float* lamy = (const float*)d_in[10];
  const float* cxp  = (const float*)d_in[11];
  const float* cyp  = (const float*)d_in[12];
  float* ws  = (float*)d_ws;
  float* o   = (float*)d_out;

  planner_setup<<<dim3(4), dim3(64), 0, stream>>>(P, Pd, Pdd, ws);
  planner_main<<<dim3(NBATCH), dim3(128), 0, stream>>>(
      P, Pd, Pdd, init, fin, cobs, vobs, yub, ylb, lamx, lamy, cxp, cyp, ws, o);
}